// Round 16
// baseline (169.019 us; speedup 1.0000x reference)
//
#include <hip/hip_runtime.h>

// VectorQuantizer: x (32,64,64,64) f32, codebook (1024,64) f32
// out = concat( quantized (32,64,64,64) f32 , indices (32,64,64) as f32 )
//
// R20 = ONE kernel. R19's verified ring/math + in-loop codebook conversion
// (prep deleted), inline rescan reads cb directly.
//  - R19 post-mortem: deleting the rescan kernel+boundary = -24.6us gross,
//    main +9.5 -> total 140.9. Boundaries are the remaining budget.
//  - prep fused WITHOUT R16's spin-gate: no shared stream. Per chunk, each
//    wave (ci=wv>>1, role=wv&1) loads 4 float4 of raw cb (L2-resident),
//    converts with prep's VERBATIM expressions (bh2 = -2*f16(b); rb2k =
//    f16(-4096*(b-f16(b)))), ds_writes into the same chunk layout ->
//    CT_BODY byte-identical. Compiler handles load->use waits (per-reg
//    counted vmcnt); 1 barrier/iter, 2-slot ring, preA/preB 2-unroll.
//  - cn rides the bh2 wave: 16 fmaf + 2 shfl_xor per chunk -> cnq_lds for
//    exactly the cts the next iter consumes. No norm pass anywhere.
//  - inline rescan: direct row-major cb + inline norm (exact f32 argmin).
//  - tripwires: FETCH ~20-24MB / WRITE ~34MB (spill), VGPR < ~200,
//    absmax 0. Falsification: total >= 138 -> revert R19, declare plateau.

typedef _Float16 f16x8 __attribute__((ext_vector_type(8)));
typedef float    f32x4 __attribute__((ext_vector_type(4)));

#define VQ_D    64
#define VQ_HW   4096
#define VQ_NPOS 131072
#define SC      2048.0f
#define EPS_Q   24         // flag margin in q-units (24/2048 = 1.17e-2)

__device__ __forceinline__ f16x8 pack_bh2(float4 u, float4 v)
{
    const float s[8] = {u.x, u.y, u.z, u.w, v.x, v.y, v.z, v.w};
    f16x8 o;
    #pragma unroll
    for (int j = 0; j < 8; ++j) {
        const _Float16 bh = (_Float16)s[j];
        o[j] = (_Float16)(-2.0f * (float)bh);        // exact (pow2 scale)
    }
    return o;
}

__device__ __forceinline__ f16x8 pack_rb2k(float4 u, float4 v)
{
    const float s[8] = {u.x, u.y, u.z, u.w, v.x, v.y, v.z, v.w};
    f16x8 o;
    #pragma unroll
    for (int j = 0; j < 8; ++j) {
        const _Float16 bh = (_Float16)s[j];
        o[j] = (_Float16)((s[j] - (float)bh) * (-2.0f * SC));
    }
    return o;
}

// load chunk C's slice for this lane: row n=(2C+ci)*16+(lane&15),
// floats [k0,k0+8) and [32+k0, 32+k0+8)  (k0 = (lane>>4)*8)
#define LDCHUNK(C, P0, P1, P2, P3)                                            \
    {                                                                         \
        const float* rw_ = cb + (size_t)(((C) * 2 + ci) * 16 + (lane & 15)) * 64 + k0x; \
        P0 = ((const float4*)rw_)[0];       P1 = ((const float4*)rw_)[1];     \
        P2 = ((const float4*)(rw_ + 32))[0]; P3 = ((const float4*)(rw_ + 32))[1]; \
    }

// convert chunk C (regs P0..P3) -> ring slot byte-offset SLOTB; bh2-role
// waves also compute + store cn_q for their ct (=2C+ci).
#define CONVW(P0, P1, P2, P3, SLOTB, C)                                       \
    {                                                                         \
        char* wb_ = (char*)bbuf + (SLOTB) + ci * 4096 + role * 2048 + lane * 16; \
        if (role == 0) {                                                      \
            *(f16x8*)wb_          = pack_bh2(P0, P1);                         \
            *(f16x8*)(wb_ + 1024) = pack_bh2(P2, P3);                         \
            float na_ = 0.f;                                                  \
            na_ = fmaf(P0.x, P0.x, na_); na_ = fmaf(P0.y, P0.y, na_);         \
            na_ = fmaf(P0.z, P0.z, na_); na_ = fmaf(P0.w, P0.w, na_);         \
            na_ = fmaf(P1.x, P1.x, na_); na_ = fmaf(P1.y, P1.y, na_);         \
            na_ = fmaf(P1.z, P1.z, na_); na_ = fmaf(P1.w, P1.w, na_);         \
            na_ = fmaf(P2.x, P2.x, na_); na_ = fmaf(P2.y, P2.y, na_);         \
            na_ = fmaf(P2.z, P2.z, na_); na_ = fmaf(P2.w, P2.w, na_);         \
            na_ = fmaf(P3.x, P3.x, na_); na_ = fmaf(P3.y, P3.y, na_);         \
            na_ = fmaf(P3.z, P3.z, na_); na_ = fmaf(P3.w, P3.w, na_);         \
            na_ += __shfl_xor(na_, 16, 64);                                   \
            na_ += __shfl_xor(na_, 32, 64);                                   \
            if (lane < 16) cnq_lds[(C) * 32 + ci * 16 + lane] = na_ * 2048.0f;\
        } else {                                                              \
            *(f16x8*)wb_          = pack_rb2k(P0, P1);                        \
            *(f16x8*)(wb_ + 1024) = pack_rb2k(P2, P3);                        \
        }                                                                     \
    }

// one 16-code tile, 4 M-tiles (verified R15/R19 math, byte-identical)
#define CT_BODY(BOFF, CI, CTG)                                                \
    {                                                                         \
        const f16x8 B0 = *(const f16x8*)(lp + (BOFF) + (CI) * 4096);          \
        const f16x8 B1 = *(const f16x8*)(lp + (BOFF) + (CI) * 4096 + 1024);   \
        const f16x8 R0 = *(const f16x8*)(lp + (BOFF) + (CI) * 4096 + 2048);   \
        const f16x8 R1 = *(const f16x8*)(lp + (BOFF) + (CI) * 4096 + 3072);   \
        const float cvq = cnq_lds[(CTG) * 16 + m];                            \
        const f32x4 Ci = {cvq, cvq, cvq, cvq};                                \
        f32x4 pa[4], pb[4];                                                   \
        __builtin_amdgcn_s_setprio(1);                                        \
        _Pragma("unroll")                                                     \
        for (int tl = 0; tl < 4; ++tl) {                                      \
            pa[tl] = __builtin_amdgcn_mfma_f32_16x16x32_f16(Ak[tl][0], B0, Ci,    0,0,0); \
            pb[tl] = __builtin_amdgcn_mfma_f32_16x16x32_f16(Ak[tl][1], B1, zero4, 0,0,0); \
        }                                                                     \
        _Pragma("unroll")                                                     \
        for (int tl = 0; tl < 4; ++tl) {                                      \
            pa[tl] = __builtin_amdgcn_mfma_f32_16x16x32_f16(Ah[tl][0], R0, pa[tl], 0,0,0); \
            pb[tl] = __builtin_amdgcn_mfma_f32_16x16x32_f16(Ah[tl][1], R1, pb[tl], 0,0,0); \
        }                                                                     \
        _Pragma("unroll")                                                     \
        for (int tl = 0; tl < 4; ++tl) {                                      \
            pa[tl] = __builtin_amdgcn_mfma_f32_16x16x32_f16(Ra[tl][0], B0, pa[tl], 0,0,0); \
            pb[tl] = __builtin_amdgcn_mfma_f32_16x16x32_f16(Ra[tl][1], B1, pb[tl], 0,0,0); \
        }                                                                     \
        __builtin_amdgcn_s_setprio(0);                                        \
        const int cbase_ = (CTG) * 16 + m;                                    \
        _Pragma("unroll")                                                     \
        for (int tl = 0; tl < 4; ++tl)                                        \
            _Pragma("unroll")                                                 \
            for (int r = 0; r < 4; ++r) {                                     \
                const float q_ = pa[tl][r] + pb[tl][r];                       \
                const int k_ = ((int)q_ << 10) | cbase_;                      \
                int md_;                                                      \
                asm("v_med3_i32 %0, %1, %2, %3"                               \
                    : "=v"(md_) : "v"(k_), "v"(d1[tl][r]), "v"(d2[tl][r]));   \
                d2[tl][r] = md_;                                              \
                d1[tl][r] = (k_ < d1[tl][r]) ? k_ : d1[tl][r];                \
            }                                                                 \
    }

#define COMPUTE(T)                                                            \
    {                                                                         \
        const int base_ = ((T) & 1) * 8192;                                   \
        CT_BODY(base_, 0, (T) * 2)                                            \
        CT_BODY(base_, 1, (T) * 2 + 1)                                        \
    }

__global__ __launch_bounds__(256, 2)
void vq_main(const float* __restrict__ x,
             const float* __restrict__ cb,
             float* __restrict__ out,
             float* __restrict__ idx_out)
{
    __shared__ f16x8 bbuf[2 * 512];   // 2-slot ring, 8KB (2 ct) per slot
    __shared__ float cnq_lds[1024];   // 2048*||e||^2, filled per chunk
    __shared__ int   sk[256];
    __shared__ int   smg[256];
    __shared__ int   lpos[256];       // flagged-position list (block-local)
    __shared__ int   lcnt;

    const int tid  = threadIdx.x;
    const int lane = tid & 63;
    const int wv   = tid >> 6;        // 4 waves, 64 positions each
    const int m    = lane & 15;
    const int q    = lane >> 4;
    const int ci   = wv >> 1;         // which ct of the chunk this wave stages
    const int role = wv & 1;          // 0: bh2 + norm, 1: rb2k
    const int k0x  = (lane >> 4) * 8; // dim offset within row

    const int p0 = blockIdx.x * 256;  // block: 256 consecutive positions
    const int b  = p0 >> 12;
    const int n0 = p0 & (VQ_HW - 1);
    const float* xw = x + (size_t)b * (VQ_D * VQ_HW) + n0 + wv * 64;

    // ---- A fragments: hi, 2048*hi (exact), scaled residual; 4 M-tiles ----
    f16x8 Ah[4][2], Ak[4][2], Ra[4][2];
    #pragma unroll
    for (int tl = 0; tl < 4; ++tl)
        #pragma unroll
        for (int ks = 0; ks < 2; ++ks) {
            f16x8 h8, k8, r8;
            #pragma unroll
            for (int j = 0; j < 8; ++j) {
                const float v = xw[(size_t)(ks * 32 + q * 8 + j) * VQ_HW + tl * 16 + m];
                const _Float16 vh = (_Float16)v;
                h8[j] = vh;
                k8[j] = (_Float16)((float)vh * 2048.0f);     // exact (pow2)
                r8[j] = (_Float16)((v - (float)vh) * SC);
            }
            Ah[tl][ks] = h8; Ak[tl][ks] = k8; Ra[tl][ks] = r8;
        }

    // ---- prologue: load c0,c1 to regs; convert c0 -> slot0 (+cnq cts 0,1) --
    float4 a0, a1, a2, a3, b0, b1, b2, b3;
    LDCHUNK(0, a0, a1, a2, a3)
    LDCHUNK(1, b0, b1, b2, b3)
    CONVW(a0, a1, a2, a3, 0, 0)

    int d1[4][4], d2[4][4];
    #pragma unroll
    for (int tl = 0; tl < 4; ++tl)
        #pragma unroll
        for (int r = 0; r < 4; ++r) { d1[tl][r] = 0x7FFFFFFF; d2[tl][r] = 0x7FFFFFFF; }

    const f32x4 zero4 = {0.f, 0.f, 0.f, 0.f};
    const char* lp = (const char*)bbuf + lane * 16;

    __syncthreads();   // chunk 0 + its cnq visible

    // ---- ring: 1 barrier/iter; convert t+1, prefetch t+2, compute t ----
    for (int h = 0; h < 15; ++h) {
        const int t0 = 2 * h;
        // even iter t0: convert c(t0+1) from B-set; load c(t0+2)->A; compute t0
        CONVW(b0, b1, b2, b3, 8192, t0 + 1)
        LDCHUNK(t0 + 2, a0, a1, a2, a3)
        COMPUTE(t0)
        __syncthreads();
        // odd iter t0+1: convert c(t0+2) from A; load c(t0+3)->B; compute t0+1
        CONVW(a0, a1, a2, a3, 0, t0 + 2)
        LDCHUNK(t0 + 3, b0, b1, b2, b3)
        COMPUTE(t0 + 1)
        __syncthreads();
    }
    // t=30: convert c31 from B -> slot1; compute c30 (slot0)
    CONVW(b0, b1, b2, b3, 8192, 31)
    COMPUTE(30)
    __syncthreads();
    COMPUTE(31)

    // ---- top-2 merge across the 16 code-columns (keys carry the code) ----
    #pragma unroll
    for (int off = 1; off < 16; off <<= 1)
        #pragma unroll
        for (int tl = 0; tl < 4; ++tl)
            #pragma unroll
            for (int r = 0; r < 4; ++r) {
                const int od1 = __shfl_xor(d1[tl][r], off, 64);
                const int od2 = __shfl_xor(d2[tl][r], off, 64);
                const int mx  = (d1[tl][r] > od1) ? d1[tl][r] : od1;
                const int mn2 = (d2[tl][r] < od2) ? d2[tl][r] : od2;
                d2[tl][r] = (mx < mn2) ? mx : mn2;
                d1[tl][r] = (d1[tl][r] < od1) ? d1[tl][r] : od1;
            }

    if (m == 0) {
        #pragma unroll
        for (int tl = 0; tl < 4; ++tl)
            #pragma unroll
            for (int r = 0; r < 4; ++r) {
                const int li = wv * 64 + tl * 16 + q * 4 + r;
                sk[li]  = d1[tl][r] & 1023;
                smg[li] = (d2[tl][r] >> 10) - (d1[tl][r] >> 10);   // gap, q-units
            }
    }
    if (tid == 0) lcnt = 0;
    __syncthreads();

    // ---- epilogue: indices + approximate quantized scatter ----
    const int bk = sk[tid];           // 1 thread per position
    idx_out[p0 + tid] = (float)bk;
    {
        const float4* cr = (const float4*)(cb + (size_t)bk * VQ_D);
        float* ob = out + (size_t)b * (VQ_D * VQ_HW) + n0 + tid;
        #pragma unroll
        for (int d4 = 0; d4 < 16; ++d4) {
            const float4 v = cr[d4];
            ob[(size_t)(d4 * 4 + 0) * VQ_HW] = v.x;
            ob[(size_t)(d4 * 4 + 1) * VQ_HW] = v.y;
            ob[(size_t)(d4 * 4 + 2) * VQ_HW] = v.z;
            ob[(size_t)(d4 * 4 + 3) * VQ_HW] = v.w;
        }
    }
    if (smg[tid] < EPS_Q) {           // collect flags (block-local)
        const int s_ = atomicAdd(&lcnt, 1);
        lpos[s_] = tid;
    }
    __syncthreads();

    // ---- inline exact-f32 rescan (direct cb rows + inline norm) ----
    const int nf = lcnt;
    if (nf > 0) {
        float* xsw = (float*)((char*)bbuf + wv * 1024);   // ring dead; reuse
        for (int i = wv; i < nf; i += 4) {                // waves round-robin
            const int pos = lpos[i];
            const int nn  = n0 + pos;
            xsw[lane] = x[(size_t)b * (VQ_D * VQ_HW) + (size_t)lane * VQ_HW + nn];
            float4 xr[16];
            #pragma unroll
            for (int j = 0; j < 16; ++j) xr[j] = ((const float4*)xsw)[j];

            float bd = 3.4e38f; int bk2 = 0;
            #pragma unroll 4
            for (int t = 0; t < 16; ++t) {
                const int code = t * 64 + lane;           // per-lane ascending
                const float4* row = (const float4*)(cb + (size_t)code * VQ_D);
                float d0 = 0.f, d1_ = 0.f, nr0 = 0.f, nr1 = 0.f;
                #pragma unroll
                for (int j4 = 0; j4 < 16; ++j4) {
                    const float4 c = row[j4];
                    d0  = fmaf(xr[j4].x, c.x, d0);  d1_ = fmaf(xr[j4].y, c.y, d1_);
                    d0  = fmaf(xr[j4].z, c.z, d0);  d1_ = fmaf(xr[j4].w, c.w, d1_);
                    nr0 = fmaf(c.x, c.x, nr0);      nr1 = fmaf(c.y, c.y, nr1);
                    nr0 = fmaf(c.z, c.z, nr0);      nr1 = fmaf(c.w, c.w, nr1);
                }
                const float dist = fmaf(-2.0f, d0 + d1_, nr0 + nr1);
                if (dist < bd) { bd = dist; bk2 = code; }
            }
            #pragma unroll
            for (int off = 1; off < 64; off <<= 1) {      // min dist, tie -> min k
                const float od = __shfl_xor(bd, off, 64);
                const int   ok = __shfl_xor(bk2, off, 64);
                if (od < bd || (od == bd && ok < bk2)) { bd = od; bk2 = ok; }
            }
            out[(size_t)b * (VQ_D * VQ_HW) + (size_t)lane * VQ_HW + nn] =
                cb[(size_t)bk2 * VQ_D + lane];
            if (lane == 0) idx_out[p0 + pos] = (float)bk2;
        }
    }
}

extern "C" void kernel_launch(void* const* d_in, const int* in_sizes, int n_in,
                              void* d_out, int out_size, void* d_ws, size_t ws_size,
                              hipStream_t stream) {
    const float* x  = (const float*)d_in[0];
    const float* cb = (const float*)d_in[1];
    float* out = (float*)d_out;
    float* idx = out + (size_t)VQ_NPOS * VQ_D;   // 8,388,608 floats in
    (void)d_ws; (void)ws_size;                    // workspace unused

    vq_main<<<dim3(512), dim3(256), 0, stream>>>(x, cb, out, idx);
}